// Round 7
// baseline (58.450 us; speedup 1.0000x reference)
//
#include <hip/hip_runtime.h>
#include <hip/hip_bf16.h>
#include <stdint.h>

typedef __attribute__((ext_vector_type(8))) short short8;
typedef __attribute__((ext_vector_type(4))) float f32x4;

constexpr int Tt = 8192, Kd = 1024, Nd = 1024, Gn = 8;
constexpr int BM = 128, BN = 128, BK = 64;
constexpr int NKT = Kd / BK; // 16 K-tiles

static __device__ __forceinline__ short f2bf(float x) {
    __hip_bfloat16 b = __float2bfloat16(x);
    return *reinterpret_cast<short*>(&b);
}

// ---------------- prep: W -> bf16 transposed [g][n][k] (HW-verified R5/R6) ----------------
__global__ __launch_bounds__(256)
void prep_w_kernel(const float* __restrict__ W, short* __restrict__ Wt)
{
    const int b = blockIdx.x, t = threadIdx.x;
    // 64x64 tile transpose-convert; 256 tiles/expert (16 kt x 16 nt)
    const int g = b >> 8, r = b & 255;
    const int kb = (r >> 4) * 64, nb = (r & 15) * 64;
    const float* src = W + (size_t)g * Kd * Nd + (size_t)kb * Nd + nb;
    __shared__ float Ls[64 * 64];
#pragma unroll
    for (int i = 0; i < 4; ++i) {
        const int s = i * 256 + t;
        const int k = s >> 4, gc = s & 15;
        const f32x4 v = *(const f32x4*)(src + (size_t)k * Nd + ((gc ^ (k & 15)) << 2));
        *(f32x4*)&Ls[k * 64 + (gc << 2)] = v;
    }
    __syncthreads();
    short* dst = Wt + (size_t)g * Nd * Kd + (size_t)nb * Kd + kb;
#pragma unroll
    for (int i = 0; i < 2; ++i) {
        const int s = i * 256 + t;
        const int n = s >> 3, kc = s & 7;
        short8 v;
#pragma unroll
        for (int j = 0; j < 8; ++j) {
            const int k = kc * 8 + j;
            v[j] = f2bf(Ls[k * 64 + ((((n >> 2) ^ (k & 15)) << 2) | (n & 3))]);
        }
        *(short8*)(dst + (size_t)n * Kd + kc * 8) = v;
    }
}

// ------- GEMM: m97 geometry. 128x128, 4 waves, dbuf 64KB LDS, 2 blocks/CU. -------
// A: fp32 reg-stage -> cvt -> ds_write (R4-proven). B: bf16 global_load_lds (R6-proven).
__global__ __launch_bounds__(256, 2)
void gemm_kernel(const float* __restrict__ H, const short* __restrict__ Wt,
                 const int* __restrict__ counts, float* __restrict__ out)
{
    __shared__ __align__(16) short As[2][BM * BK];   // 16 KB x2
    __shared__ __align__(16) short Bs[2][BN * BK];   // 16 KB x2

    const int tid = threadIdx.x;
    const int bid = blockIdx.x;
    const int wg = (bid & 7) * 64 + (bid >> 3);      // bijective XCD swizzle (512%8==0)
    const int mt = wg >> 3, nt = wg & 7;
    const int row0 = mt * BM, col0 = nt * BN;

    int g = 0;
    {
        int c = 0;
        for (int i = 0; i < Gn; ++i) { c += counts[i]; if (row0 >= c) g = i + 1; }
    }
    const short* __restrict__ Wg = Wt + (size_t)g * Nd * Kd;

    const int wid = tid >> 6, lane = tid & 63;
    const int wm = wid >> 1, wn = wid & 1;           // 2x2 waves, 64x64 each
    const int l15 = lane & 15, l4 = lane >> 4;

    f32x4 acc[4][4];
#pragma unroll
    for (int i = 0; i < 4; ++i)
#pragma unroll
        for (int j = 0; j < 4; ++j) acc[i][j] = (f32x4)0.0f;

    // A staging: thread -> (row ra, k-half kh); 32 floats in regs
    const int ra = tid >> 1, kh = tid & 1;
    f32x4 av[8];

    auto load_a = [&](int kt) {
        const float* p = H + (size_t)(row0 + ra) * Kd + kt * BK + kh * 32;
#pragma unroll
        for (int j = 0; j < 8; ++j) av[j] = *(const f32x4*)(p + j * 4);
    };
    auto write_a = [&](int buf) {
        const int s = ra & 7;
#pragma unroll
        for (int c = 0; c < 4; ++c) {
            short8 v;
#pragma unroll
            for (int j = 0; j < 4; ++j) { v[j] = f2bf(av[2 * c][j]); v[4 + j] = f2bf(av[2 * c + 1][j]); }
            *(short8*)&As[buf][ra * 64 + (((kh * 4 + c) ^ s) << 3)] = v;
        }
    };
    // B staging: linear LDS dest, inverse-swizzled source (m173); slot(row,gs)=granule gs^(row&7)
    auto stage_b = [&](int kt, int buf) {
#pragma unroll
        for (int i = 0; i < 4; ++i) {
            const int q = i * 4 + wid;               // 16 wave-chunks of 1KB
            const int s = q * 64 + lane;
            const int rowb = s >> 3, gc = (s & 7) ^ (rowb & 7);
            const short* src = Wg + (size_t)(col0 + rowb) * Kd + kt * BK + gc * 8;
            __builtin_amdgcn_global_load_lds(
                (const __attribute__((address_space(1))) uint32_t*)src,
                (__attribute__((address_space(3))) uint32_t*)(&Bs[buf][q * 512]),
                16, 0, 0);
        }
    };

    auto compute = [&](int buf) {
#pragma unroll
        for (int ks = 0; ks < 2; ++ks) {
            short8 af[4], bf[4];
#pragma unroll
            for (int mi = 0; mi < 4; ++mi) {
                const int m = wm * 64 + mi * 16 + l15;
                af[mi] = *(const short8*)&As[buf][m * 64 + (((ks * 4 + l4) ^ (m & 7)) << 3)];
            }
#pragma unroll
            for (int ni = 0; ni < 4; ++ni) {
                const int n = wn * 64 + ni * 16 + l15;
                bf[ni] = *(const short8*)&Bs[buf][n * 64 + (((ks * 4 + l4) ^ (n & 7)) << 3)];
            }
#pragma unroll
            for (int mi = 0; mi < 4; ++mi)
#pragma unroll
                for (int ni = 0; ni < 4; ++ni)
                    acc[mi][ni] = __builtin_amdgcn_mfma_f32_16x16x32_bf16(
                        af[mi], bf[ni], acc[mi][ni], 0, 0, 0);
        }
    };

    // prologue: tile 0
    load_a(0);
    stage_b(0, 0);
    write_a(0);
    __syncthreads();                                 // drains gload + ds_write

    int buf = 0;
    for (int kt = 0; kt < NKT; ++kt) {
        const bool more = (kt + 1 < NKT);
        if (more) { stage_b(kt + 1, buf ^ 1); load_a(kt + 1); }  // issue early (T14)
        compute(buf);
        if (more) write_a(buf ^ 1);                  // cvt+write after compute
        __syncthreads();
        buf ^= 1;
    }

    // epilogue: C/D layout col=lane&15, row=(lane>>4)*4+reg (m89-verified)
#pragma unroll
    for (int mi = 0; mi < 4; ++mi) {
        const int rbase = row0 + wm * 64 + mi * 16 + l4 * 4;
#pragma unroll
        for (int ni = 0; ni < 4; ++ni) {
            const int c = col0 + wn * 64 + ni * 16 + l15;
#pragma unroll
            for (int r = 0; r < 4; ++r)
                out[(size_t)(rbase + r) * Nd + c] = acc[mi][ni][r];
        }
    }
}

// ---------------- fallback (round-4 kernel, in-loop W transpose) if ws too small ----------------
__global__ __launch_bounds__(512, 2)
void gemm_f32_fallback(const float* __restrict__ H, const float* __restrict__ W,
                       const int* __restrict__ counts, float* __restrict__ out)
{
    constexpr int FBN = 256;
    __shared__ __align__(16) short As[2][BM * BK];
    __shared__ __align__(16) short Bs2[2][FBN * BK];
    const int tid = threadIdx.x, bid = blockIdx.x;
    const int swz = (bid & 7) * 32 + (bid >> 3);
    const int mt = swz >> 2, nt = swz & 3;
    const int row0 = mt * BM, col0 = nt * FBN;
    int g = 0; { int c = 0; for (int i = 0; i < Gn; ++i) { c += counts[i]; if (row0 >= c) g = i + 1; } }
    const float* __restrict__ Wg = W + (size_t)g * Kd * Nd;
    const int wid = tid >> 6, lane = tid & 63;
    const int wm = wid >> 2, wn = wid & 3;
    const int l15 = lane & 15, l4 = lane >> 4;
    const int ra = tid >> 2, ca = tid & 3;
    const int nb = tid & 255, kh = tid >> 8;
    f32x4 acc[4][4];
#pragma unroll
    for (int i = 0; i < 4; ++i)
#pragma unroll
        for (int j = 0; j < 4; ++j) acc[i][j] = (f32x4)0.0f;
    f32x4 av[4]; float bv[32];
    auto load_a = [&](int kt) {
        const float* p = H + (size_t)(row0 + ra) * Kd + kt * BK + ca * 16;
#pragma unroll
        for (int j = 0; j < 4; ++j) av[j] = *(const f32x4*)(p + j * 4);
    };
    auto load_b = [&](int kt) {
        const float* p = Wg + (size_t)(kt * BK + kh * 32) * Nd + col0 + nb;
#pragma unroll
        for (int j = 0; j < 32; ++j) bv[j] = p[(size_t)j * Nd];
    };
    auto write_a = [&](int buf) {
        short8 v0, v1;
#pragma unroll
        for (int j = 0; j < 4; ++j) {
            v0[j] = f2bf(av[0][j]); v0[4 + j] = f2bf(av[1][j]);
            v1[j] = f2bf(av[2][j]); v1[4 + j] = f2bf(av[3][j]);
        }
        const int s = ra & 7;
        *(short8*)&As[buf][ra * 64 + (((ca * 2) ^ s) << 3)] = v0;
        *(short8*)&As[buf][ra * 64 + (((ca * 2 + 1) ^ s) << 3)] = v1;
    };
    auto write_b = [&](int buf) {
        const int s = nb & 7;
#pragma unroll
        for (int c = 0; c < 4; ++c) {
            short8 v;
#pragma unroll
            for (int j = 0; j < 8; ++j) v[j] = f2bf(bv[c * 8 + j]);
            *(short8*)&Bs2[buf][nb * 64 + (((kh * 4 + c) ^ s) << 3)] = v;
        }
    };
    auto compute = [&](int buf) {
#pragma unroll
        for (int ks = 0; ks < 2; ++ks) {
            short8 af[4], bf[4];
#pragma unroll
            for (int mi = 0; mi < 4; ++mi) {
                const int m = wm * 64 + mi * 16 + l15;
                af[mi] = *(const short8*)&As[buf][m * 64 + (((ks * 4 + l4) ^ (m & 7)) << 3)];
            }
#pragma unroll
            for (int ni = 0; ni < 4; ++ni) {
                const int n = wn * 64 + ni * 16 + l15;
                bf[ni] = *(const short8*)&Bs2[buf][n * 64 + (((ks * 4 + l4) ^ (n & 7)) << 3)];
            }
#pragma unroll
            for (int mi = 0; mi < 4; ++mi)
#pragma unroll
                for (int ni = 0; ni < 4; ++ni)
                    acc[mi][ni] = __builtin_amdgcn_mfma_f32_16x16x32_bf16(
                        af[mi], bf[ni], acc[mi][ni], 0, 0, 0);
        }
    };
    load_a(0); load_b(0); write_a(0); write_b(0);
    __syncthreads();
    int buf = 0;
    for (int kt = 0; kt < NKT; ++kt) {
        const bool more = (kt + 1 < NKT);
        if (more) { load_a(kt + 1); load_b(kt + 1); }
        compute(buf);
        if (more) { write_a(buf ^ 1); write_b(buf ^ 1); }
        __syncthreads();
        buf ^= 1;
    }
#pragma unroll
    for (int mi = 0; mi < 4; ++mi) {
        const int rbase = row0 + wm * 64 + mi * 16 + l4 * 4;
#pragma unroll
        for (int ni = 0; ni < 4; ++ni) {
            const int c = col0 + wn * 64 + ni * 16 + l15;
#pragma unroll
            for (int r = 0; r < 4; ++r)
                out[(size_t)(rbase + r) * Nd + c] = acc[mi][ni][r];
        }
    }
}

extern "C" void kernel_launch(void* const* d_in, const int* in_sizes, int n_in,
                              void* d_out, int out_size, void* d_ws, size_t ws_size,
                              hipStream_t stream) {
    const float* H = (const float*)d_in[0];
    const float* W = (const float*)d_in[1];
    const int* counts = (const int*)d_in[2];
    float* out = (float*)d_out;
    const size_t need = (size_t)Gn * Kd * Nd * sizeof(short); // 16 MB
    if (ws_size >= need) {
        short* Wt = (short*)d_ws;
        prep_w_kernel<<<2048, 256, 0, stream>>>(W, Wt);
        gemm_kernel<<<512, 256, 0, stream>>>(H, Wt, counts, out);
    } else {
        gemm_f32_fallback<<<256, 512, 0, stream>>>(H, W, counts, out);
    }
}

// Round 8
// 58.359 us; speedup vs baseline: 1.0016x; 1.0016x over previous
//
#include <hip/hip_runtime.h>
#include <hip/hip_bf16.h>
#include <stdint.h>

typedef __attribute__((ext_vector_type(8))) short short8;
typedef __attribute__((ext_vector_type(4))) float f32x4;

constexpr int Tt = 8192, Kd = 1024, Nd = 1024, Gn = 8;
constexpr int BM = 128, BN = 128, BK = 64;
constexpr int NKT = Kd / BK; // 16 K-tiles

static __device__ __forceinline__ short f2bf(float x) {
    __hip_bfloat16 b = __float2bfloat16(x);
    return *reinterpret_cast<short*>(&b);
}

// ---------------- prep: W -> bf16 transposed [g][n][k] (HW-verified R5-R7) ----------------
__global__ __launch_bounds__(256)
void prep_w_kernel(const float* __restrict__ W, short* __restrict__ Wt)
{
    const int b = blockIdx.x, t = threadIdx.x;
    const int g = b >> 8, r = b & 255;
    const int kb = (r >> 4) * 64, nb = (r & 15) * 64;
    const float* src = W + (size_t)g * Kd * Nd + (size_t)kb * Nd + nb;
    __shared__ float Ls[64 * 64];
#pragma unroll
    for (int i = 0; i < 4; ++i) {
        const int s = i * 256 + t;
        const int k = s >> 4, gc = s & 15;
        const f32x4 v = *(const f32x4*)(src + (size_t)k * Nd + ((gc ^ (k & 15)) << 2));
        *(f32x4*)&Ls[k * 64 + (gc << 2)] = v;
    }
    __syncthreads();
    short* dst = Wt + (size_t)g * Nd * Kd + (size_t)nb * Kd + kb;
#pragma unroll
    for (int i = 0; i < 2; ++i) {
        const int s = i * 256 + t;
        const int n = s >> 3, kc = s & 7;
        short8 v;
#pragma unroll
        for (int j = 0; j < 8; ++j) {
            const int k = kc * 8 + j;
            v[j] = f2bf(Ls[k * 64 + ((((n >> 2) ^ (k & 15)) << 2) | (n & 3))]);
        }
        *(short8*)(dst + (size_t)n * Kd + kc * 8) = v;
    }
}

// ---- GEMM: 128x128, 4 waves, 2 blocks/CU. A: fp32 reg->cvt->ds_write (dbuf).
// ---- B: bf16 gload_lds, TRI-buffer, depth-2 prefetch, counted vmcnt (never 0 in loop).
__global__ __launch_bounds__(256, 2)
void gemm_kernel(const float* __restrict__ H, const short* __restrict__ Wt,
                 const int* __restrict__ counts, float* __restrict__ out)
{
    __shared__ __align__(16) short As[2][BM * BK];   // 32 KB
    __shared__ __align__(16) short Bs[3][BN * BK];   // 48 KB -> 80 KB total

    const int tid = threadIdx.x;
    const int bid = blockIdx.x;
    const int wg = (bid & 7) * 64 + (bid >> 3);      // bijective XCD swizzle (512%8==0)
    const int mt = wg >> 3, nt = wg & 7;
    const int row0 = mt * BM, col0 = nt * BN;

    int g = 0;
    {
        int c = 0;
        for (int i = 0; i < Gn; ++i) { c += counts[i]; if (row0 >= c) g = i + 1; }
    }
    const short* __restrict__ Wg = Wt + (size_t)g * Nd * Kd;

    const int wid = tid >> 6, lane = tid & 63;
    const int wm = wid >> 1, wn = wid & 1;           // 2x2 waves, 64x64 each
    const int l15 = lane & 15, l4 = lane >> 4;

    f32x4 acc[4][4];
#pragma unroll
    for (int i = 0; i < 4; ++i)
#pragma unroll
        for (int j = 0; j < 4; ++j) acc[i][j] = (f32x4)0.0f;

    // A staging: thread -> (row ra, k-half kh); 32 floats in regs
    const int ra = tid >> 1, kh = tid & 1;
    f32x4 av[8];

    auto load_a = [&](int kt) {                      // 8 dwordx4 per thread
        const float* p = H + (size_t)(row0 + ra) * Kd + kt * BK + kh * 32;
#pragma unroll
        for (int j = 0; j < 8; ++j) av[j] = *(const f32x4*)(p + j * 4);
    };
    auto write_a = [&](int buf) {                    // cvt + 4 swizzled ds_write_b128
        const int s = ra & 7;
#pragma unroll
        for (int c = 0; c < 4; ++c) {
            short8 v;
#pragma unroll
            for (int j = 0; j < 4; ++j) { v[j] = f2bf(av[2 * c][j]); v[4 + j] = f2bf(av[2 * c + 1][j]); }
            *(short8*)&As[buf][ra * 64 + (((kh * 4 + c) ^ s) << 3)] = v;
        }
    };
    // B: linear LDS dest, inverse-swizzled source (m173); slot(row,gs)=granule gs^(row&7)
    auto stage_b = [&](int kt, int buf) {            // 4 gload_lds per wave
#pragma unroll
        for (int i = 0; i < 4; ++i) {
            const int q = i * 4 + wid;               // 16 wave-chunks of 1KB
            const int s = q * 64 + lane;
            const int rowb = s >> 3, gc = (s & 7) ^ (rowb & 7);
            const short* src = Wg + (size_t)(col0 + rowb) * Kd + kt * BK + gc * 8;
            __builtin_amdgcn_global_load_lds(
                (const __attribute__((address_space(1))) uint32_t*)src,
                (__attribute__((address_space(3))) uint32_t*)(&Bs[buf][q * 512]),
                16, 0, 0);
        }
    };

    auto compute = [&](int bufA, int bufB) {
#pragma unroll
        for (int ks = 0; ks < 2; ++ks) {
            short8 af[4], bf[4];
#pragma unroll
            for (int mi = 0; mi < 4; ++mi) {
                const int m = wm * 64 + mi * 16 + l15;
                af[mi] = *(const short8*)&As[bufA][m * 64 + (((ks * 4 + l4) ^ (m & 7)) << 3)];
            }
#pragma unroll
            for (int ni = 0; ni < 4; ++ni) {
                const int n = wn * 64 + ni * 16 + l15;
                bf[ni] = *(const short8*)&Bs[bufB][n * 64 + (((ks * 4 + l4) ^ (n & 7)) << 3)];
            }
#pragma unroll
            for (int mi = 0; mi < 4; ++mi)
#pragma unroll
                for (int ni = 0; ni < 4; ++ni)
                    acc[mi][ni] = __builtin_amdgcn_mfma_f32_16x16x32_bf16(
                        af[mi], bf[ni], acc[mi][ni], 0, 0, 0);
        }
    };

    // prologue: A0 regs, B0+B1 in flight; write A0; publish tile 0.
    load_a(0);                                       // A0: 8 loads
    stage_b(0, 0);                                   // B0: 4
    stage_b(1, 1);                                   // B1: 4
    write_a(0);                                      // compiler waits vmcnt(8) for A0
    asm volatile("s_waitcnt vmcnt(4) lgkmcnt(0)" ::: "memory");  // B0 landed; B1 in flight
    __builtin_amdgcn_s_barrier();

    int bufB = 0;
    for (int kt = 0; kt < NKT; ++kt) {
        const bool pf1 = (kt + 1 < NKT), pf2 = (kt + 2 < NKT);
        if (pf1) load_a(kt + 1);                     // A loads FIRST (younger B keeps
        if (pf2) stage_b(kt + 2, (bufB + 2) % 3);    //  A's reg-dep wait at vmcnt(4))
        compute(kt & 1, bufB);
        if (pf1) write_a((kt + 1) & 1);              // waits A(kt+1) via vmcnt(4)
        if (pf1) {
            // publish tile kt+1: B(kt+1) landed (only B(kt+2)'s 4 may stay in flight)
            if (pf2) asm volatile("s_waitcnt vmcnt(4) lgkmcnt(0)" ::: "memory");
            else     asm volatile("s_waitcnt vmcnt(0) lgkmcnt(0)" ::: "memory");
            __builtin_amdgcn_s_barrier();
        }
        bufB = (bufB + 1) % 3;
    }

    // epilogue: C/D layout col=lane&15, row=(lane>>4)*4+reg (m89-verified)
#pragma unroll
    for (int mi = 0; mi < 4; ++mi) {
        const int rbase = row0 + wm * 64 + mi * 16 + l4 * 4;
#pragma unroll
        for (int ni = 0; ni < 4; ++ni) {
            const int c = col0 + wn * 64 + ni * 16 + l15;
#pragma unroll
            for (int r = 0; r < 4; ++r)
                out[(size_t)(rbase + r) * Nd + c] = acc[mi][ni][r];
        }
    }
}

// ---------------- fallback (round-4 kernel, fused, 39.2us) if ws too small ----------------
__global__ __launch_bounds__(512, 2)
void gemm_f32_fallback(const float* __restrict__ H, const float* __restrict__ W,
                       const int* __restrict__ counts, float* __restrict__ out)
{
    constexpr int FBN = 256;
    __shared__ __align__(16) short As[2][BM * BK];
    __shared__ __align__(16) short Bs2[2][FBN * BK];
    const int tid = threadIdx.x, bid = blockIdx.x;
    const int swz = (bid & 7) * 32 + (bid >> 3);
    const int mt = swz >> 2, nt = swz & 3;
    const int row0 = mt * BM, col0 = nt * FBN;
    int g = 0; { int c = 0; for (int i = 0; i < Gn; ++i) { c += counts[i]; if (row0 >= c) g = i + 1; } }
    const float* __restrict__ Wg = W + (size_t)g * Kd * Nd;
    const int wid = tid >> 6, lane = tid & 63;
    const int wm = wid >> 2, wn = wid & 3;
    const int l15 = lane & 15, l4 = lane >> 4;
    const int ra = tid >> 2, ca = tid & 3;
    const int nb = tid & 255, kh = tid >> 8;
    f32x4 acc[4][4];
#pragma unroll
    for (int i = 0; i < 4; ++i)
#pragma unroll
        for (int j = 0; j < 4; ++j) acc[i][j] = (f32x4)0.0f;
    f32x4 av[4]; float bv[32];
    auto load_a = [&](int kt) {
        const float* p = H + (size_t)(row0 + ra) * Kd + kt * BK + ca * 16;
#pragma unroll
        for (int j = 0; j < 4; ++j) av[j] = *(const f32x4*)(p + j * 4);
    };
    auto load_b = [&](int kt) {
        const float* p = Wg + (size_t)(kt * BK + kh * 32) * Nd + col0 + nb;
#pragma unroll
        for (int j = 0; j < 32; ++j) bv[j] = p[(size_t)j * Nd];
    };
    auto write_a = [&](int buf) {
        short8 v0, v1;
#pragma unroll
        for (int j = 0; j < 4; ++j) {
            v0[j] = f2bf(av[0][j]); v0[4 + j] = f2bf(av[1][j]);
            v1[j] = f2bf(av[2][j]); v1[4 + j] = f2bf(av[3][j]);
        }
        const int s = ra & 7;
        *(short8*)&As[buf][ra * 64 + (((ca * 2) ^ s) << 3)] = v0;
        *(short8*)&As[buf][ra * 64 + (((ca * 2 + 1) ^ s) << 3)] = v1;
    };
    auto write_b = [&](int buf) {
        const int s = nb & 7;
#pragma unroll
        for (int c = 0; c < 4; ++c) {
            short8 v;
#pragma unroll
            for (int j = 0; j < 8; ++j) v[j] = f2bf(bv[c * 8 + j]);
            *(short8*)&Bs2[buf][nb * 64 + (((kh * 4 + c) ^ s) << 3)] = v;
        }
    };
    auto compute = [&](int buf) {
#pragma unroll
        for (int ks = 0; ks < 2; ++ks) {
            short8 af[4], bf[4];
#pragma unroll
            for (int mi = 0; mi < 4; ++mi) {
                const int m = wm * 64 + mi * 16 + l15;
                af[mi] = *(const short8*)&As[buf][m * 64 + (((ks * 4 + l4) ^ (m & 7)) << 3)];
            }
#pragma unroll
            for (int ni = 0; ni < 4; ++ni) {
                const int n = wn * 64 + ni * 16 + l15;
                bf[ni] = *(const short8*)&Bs2[buf][n * 64 + (((ks * 4 + l4) ^ (n & 7)) << 3)];
            }
#pragma unroll
            for (int mi = 0; mi < 4; ++mi)
#pragma unroll
                for (int ni = 0; ni < 4; ++ni)
                    acc[mi][ni] = __builtin_amdgcn_mfma_f32_16x16x32_bf16(
                        af[mi], bf[ni], acc[mi][ni], 0, 0, 0);
        }
    };
    load_a(0); load_b(0); write_a(0); write_b(0);
    __syncthreads();
    int buf = 0;
    for (int kt = 0; kt < NKT; ++kt) {
        const bool more = (kt + 1 < NKT);
        if (more) { load_a(kt + 1); load_b(kt + 1); }
        compute(buf);
        if (more) { write_a(buf ^ 1); write_b(buf ^ 1); }
        __syncthreads();
        buf ^= 1;
    }
#pragma unroll
    for (int mi = 0; mi < 4; ++mi) {
        const int rbase = row0 + wm * 64 + mi * 16 + l4 * 4;
#pragma unroll
        for (int ni = 0; ni < 4; ++ni) {
            const int c = col0 + wn * 64 + ni * 16 + l15;
#pragma unroll
            for (int r = 0; r < 4; ++r)
                out[(size_t)(rbase + r) * Nd + c] = acc[mi][ni][r];
        }
    }
}

extern "C" void kernel_launch(void* const* d_in, const int* in_sizes, int n_in,
                              void* d_out, int out_size, void* d_ws, size_t ws_size,
                              hipStream_t stream) {
    const float* H = (const float*)d_in[0];
    const float* W = (const float*)d_in[1];
    const int* counts = (const int*)d_in[2];
    float* out = (float*)d_out;
    const size_t need = (size_t)Gn * Kd * Nd * sizeof(short); // 16 MB
    if (ws_size >= need) {
        short* Wt = (short*)d_ws;
        prep_w_kernel<<<2048, 256, 0, stream>>>(W, Wt);
        gemm_kernel<<<512, 256, 0, stream>>>(H, Wt, counts, out);
    } else {
        gemm_f32_fallback<<<256, 512, 0, stream>>>(H, W, counts, out);
    }
}

// Round 9
// 43.469 us; speedup vs baseline: 1.3446x; 1.3425x over previous
//
#include <hip/hip_runtime.h>
#include <hip/hip_bf16.h>
#include <stdint.h>

typedef __attribute__((ext_vector_type(8))) short short8;
typedef __attribute__((ext_vector_type(4))) short short4s;
typedef __attribute__((ext_vector_type(4))) float f32x4;

constexpr int Tt = 8192, Kd = 1024, Nd = 1024, Gn = 8;
constexpr int BM = 128, BN = 128, BK = 64;
constexpr int NKT = Kd / BK; // 16 K-tiles

static __device__ __forceinline__ short f2bf(float x) {
    __hip_bfloat16 b = __float2bfloat16(x);
    return *reinterpret_cast<short*>(&b);
}

// ---------------- prep: H -> bf16, W -> bf16 transposed [g][n][k] (R5-verified) ----------------
__global__ __launch_bounds__(256)
void prep_kernel(const float* __restrict__ H, const float* __restrict__ W,
                 short* __restrict__ Hb, short* __restrict__ Wt)
{
    const int b = blockIdx.x, t = threadIdx.x;
    if (b < 2048) {
        const int g = b >> 8, r = b & 255;
        const int kb = (r >> 4) * 64, nb = (r & 15) * 64;
        const float* src = W + (size_t)g * Kd * Nd + (size_t)kb * Nd + nb;
        __shared__ float Ls[64 * 64];
#pragma unroll
        for (int i = 0; i < 4; ++i) {
            const int s = i * 256 + t;
            const int k = s >> 4, gc = s & 15;
            const f32x4 v = *(const f32x4*)(src + (size_t)k * Nd + ((gc ^ (k & 15)) << 2));
            *(f32x4*)&Ls[k * 64 + (gc << 2)] = v;
        }
        __syncthreads();
        short* dst = Wt + (size_t)g * Nd * Kd + (size_t)nb * Kd + kb;
#pragma unroll
        for (int i = 0; i < 2; ++i) {
            const int s = i * 256 + t;
            const int n = s >> 3, kc = s & 7;
            short8 v;
#pragma unroll
            for (int j = 0; j < 8; ++j) {
                const int k = kc * 8 + j;
                v[j] = f2bf(Ls[k * 64 + ((((n >> 2) ^ (k & 15)) << 2) | (n & 3))]);
            }
            *(short8*)(dst + (size_t)n * Kd + kc * 8) = v;
        }
    } else {
        const int hb = b - 2048;
#pragma unroll
        for (int i = 0; i < 8; ++i) {
            const size_t gidx = (size_t)i * 262144 + (size_t)hb * 256 + t;
            const f32x4 x = *(const f32x4*)(H + gidx * 4);
            short4s v;
#pragma unroll
            for (int j = 0; j < 4; ++j) v[j] = f2bf(x[j]);
            *(short4s*)(Hb + gidx * 4) = v;
        }
    }
}

// ---- GEMM: all-bf16, pure global_load_lds (ZERO reg-staging deps in K-loop).
// ---- 128x128, 256 thr, A dbuf(32KB)+B tri(48KB)=80KB -> 2 blocks/CU.
// ---- One counted-vmcnt barrier per tile (R5 schedule + occupancy fix).
__global__ __launch_bounds__(256, 2)
void gemm_kernel(const short* __restrict__ Hb, const short* __restrict__ Wt,
                 const int* __restrict__ counts, float* __restrict__ out)
{
    __shared__ __align__(16) short As[2][BM * BK];   // 32 KB
    __shared__ __align__(16) short Bs[3][BN * BK];   // 48 KB

    const int tid = threadIdx.x;
    const int bid = blockIdx.x;
    const int wg = (bid & 7) * 64 + (bid >> 3);      // bijective XCD swizzle (512%8==0)
    const int mt = wg >> 3, nt = wg & 7;
    const int row0 = mt * BM, col0 = nt * BN;

    int g = 0;
    {
        int c = 0;
        for (int i = 0; i < Gn; ++i) { c += counts[i]; if (row0 >= c) g = i + 1; }
    }
    const short* __restrict__ Wg = Wt + (size_t)g * Nd * Kd;

    const int wid = tid >> 6, lane = tid & 63;
    const int wm = wid >> 1, wn = wid & 1;           // 2x2 waves, 64x64 each
    const int l15 = lane & 15, l4 = lane >> 4;

    f32x4 acc[4][4];
#pragma unroll
    for (int i = 0; i < 4; ++i)
#pragma unroll
        for (int j = 0; j < 4; ++j) acc[i][j] = (f32x4)0.0f;

    // linear LDS dest, inverse-swizzled source (m173); LDS slot(row,gs) = granule gs^(row&7)
    auto stage_a = [&](int kt, int buf) {            // 4 gload_lds per wave
#pragma unroll
        for (int i = 0; i < 4; ++i) {
            const int q = i * 4 + wid;               // 16 wave-chunks of 1KB
            const int s = q * 64 + lane;
            const int row = s >> 3, gc = (s & 7) ^ (row & 7);
            const short* src = Hb + (size_t)(row0 + row) * Kd + kt * BK + gc * 8;
            __builtin_amdgcn_global_load_lds(
                (const __attribute__((address_space(1))) uint32_t*)src,
                (__attribute__((address_space(3))) uint32_t*)(&As[buf][q * 512]),
                16, 0, 0);
        }
    };
    auto stage_b = [&](int kt, int buf) {            // 4 gload_lds per wave
#pragma unroll
        for (int i = 0; i < 4; ++i) {
            const int q = i * 4 + wid;
            const int s = q * 64 + lane;
            const int row = s >> 3, gc = (s & 7) ^ (row & 7);
            const short* src = Wg + (size_t)(col0 + row) * Kd + kt * BK + gc * 8;
            __builtin_amdgcn_global_load_lds(
                (const __attribute__((address_space(1))) uint32_t*)src,
                (__attribute__((address_space(3))) uint32_t*)(&Bs[buf][q * 512]),
                16, 0, 0);
        }
    };

    auto compute = [&](int bufA, int bufB) {
#pragma unroll
        for (int ks = 0; ks < 2; ++ks) {
            short8 af[4], bf[4];
#pragma unroll
            for (int mi = 0; mi < 4; ++mi) {
                const int m = wm * 64 + mi * 16 + l15;
                af[mi] = *(const short8*)&As[bufA][m * 64 + (((ks * 4 + l4) ^ (m & 7)) << 3)];
            }
#pragma unroll
            for (int ni = 0; ni < 4; ++ni) {
                const int n = wn * 64 + ni * 16 + l15;
                bf[ni] = *(const short8*)&Bs[bufB][n * 64 + (((ks * 4 + l4) ^ (n & 7)) << 3)];
            }
#pragma unroll
            for (int mi = 0; mi < 4; ++mi)
#pragma unroll
                for (int ni = 0; ni < 4; ++ni)
                    acc[mi][ni] = __builtin_amdgcn_mfma_f32_16x16x32_bf16(
                        af[mi], bf[ni], acc[mi][ni], 0, 0, 0);
        }
    };

    // prologue: A0,B0 (tile 0) + B1 in flight; wait A0+B0 (oldest 8), keep B1.
    stage_a(0, 0);
    stage_b(0, 0);
    stage_b(1, 1);
    asm volatile("s_waitcnt vmcnt(4)" ::: "memory");
    __builtin_amdgcn_s_barrier();

    int bufB = 0;
    for (int kt = 0; kt < NKT; ++kt) {
        const bool pf1 = (kt + 1 < NKT), pf2 = (kt + 2 < NKT);
        if (pf1) stage_a(kt + 1, (kt + 1) & 1);      // depth-1 A (cover = this compute)
        if (pf2) stage_b(kt + 2, (bufB + 2) % 3);    // depth-2 B
        compute(kt & 1, bufB);
        if (pf1) {
            // need A(kt+1)+B(kt+1) landed; keep B(kt+2)'s 4 in flight (T4)
            if (pf2) asm volatile("s_waitcnt vmcnt(4)" ::: "memory");
            else     asm volatile("s_waitcnt vmcnt(0)" ::: "memory");
            __builtin_amdgcn_s_barrier();
        }
        bufB = (bufB + 1) % 3;
    }

    // epilogue: C/D layout col=lane&15, row=(lane>>4)*4+reg (m89-verified)
#pragma unroll
    for (int mi = 0; mi < 4; ++mi) {
        const int rbase = row0 + wm * 64 + mi * 16 + l4 * 4;
#pragma unroll
        for (int ni = 0; ni < 4; ++ni) {
            const int c = col0 + wn * 64 + ni * 16 + l15;
#pragma unroll
            for (int r = 0; r < 4; ++r)
                out[(size_t)(rbase + r) * Nd + c] = acc[mi][ni][r];
        }
    }
}

// ---------------- fallback (round-4 kernel, fused, 39.2us) if ws too small ----------------
__global__ __launch_bounds__(512, 2)
void gemm_f32_fallback(const float* __restrict__ H, const float* __restrict__ W,
                       const int* __restrict__ counts, float* __restrict__ out)
{
    constexpr int FBN = 256;
    __shared__ __align__(16) short As[2][BM * BK];
    __shared__ __align__(16) short Bs2[2][FBN * BK];
    const int tid = threadIdx.x, bid = blockIdx.x;
    const int swz = (bid & 7) * 32 + (bid >> 3);
    const int mt = swz >> 2, nt = swz & 3;
    const int row0 = mt * BM, col0 = nt * FBN;
    int g = 0; { int c = 0; for (int i = 0; i < Gn; ++i) { c += counts[i]; if (row0 >= c) g = i + 1; } }
    const float* __restrict__ Wg = W + (size_t)g * Kd * Nd;
    const int wid = tid >> 6, lane = tid & 63;
    const int wm = wid >> 2, wn = wid & 3;
    const int l15 = lane & 15, l4 = lane >> 4;
    const int ra = tid >> 2, ca = tid & 3;
    const int nb = tid & 255, kh = tid >> 8;
    f32x4 acc[4][4];
#pragma unroll
    for (int i = 0; i < 4; ++i)
#pragma unroll
        for (int j = 0; j < 4; ++j) acc[i][j] = (f32x4)0.0f;
    f32x4 av[4]; float bv[32];
    auto load_a = [&](int kt) {
        const float* p = H + (size_t)(row0 + ra) * Kd + kt * BK + ca * 16;
#pragma unroll
        for (int j = 0; j < 4; ++j) av[j] = *(const f32x4*)(p + j * 4);
    };
    auto load_b = [&](int kt) {
        const float* p = Wg + (size_t)(kt * BK + kh * 32) * Nd + col0 + nb;
#pragma unroll
        for (int j = 0; j < 32; ++j) bv[j] = p[(size_t)j * Nd];
    };
    auto write_a = [&](int buf) {
        short8 v0, v1;
#pragma unroll
        for (int j = 0; j < 4; ++j) {
            v0[j] = f2bf(av[0][j]); v0[4 + j] = f2bf(av[1][j]);
            v1[j] = f2bf(av[2][j]); v1[4 + j] = f2bf(av[3][j]);
        }
        const int s = ra & 7;
        *(short8*)&As[buf][ra * 64 + (((ca * 2) ^ s) << 3)] = v0;
        *(short8*)&As[buf][ra * 64 + (((ca * 2 + 1) ^ s) << 3)] = v1;
    };
    auto write_b = [&](int buf) {
        const int s = nb & 7;
#pragma unroll
        for (int c = 0; c < 4; ++c) {
            short8 v;
#pragma unroll
            for (int j = 0; j < 8; ++j) v[j] = f2bf(bv[c * 8 + j]);
            *(short8*)&Bs2[buf][nb * 64 + (((kh * 4 + c) ^ s) << 3)] = v;
        }
    };
    auto compute = [&](int buf) {
#pragma unroll
        for (int ks = 0; ks < 2; ++ks) {
            short8 af[4], bf[4];
#pragma unroll
            for (int mi = 0; mi < 4; ++mi) {
                const int m = wm * 64 + mi * 16 + l15;
                af[mi] = *(const short8*)&As[buf][m * 64 + (((ks * 4 + l4) ^ (m & 7)) << 3)];
            }
#pragma unroll
            for (int ni = 0; ni < 4; ++ni) {
                const int n = wn * 64 + ni * 16 + l15;
                bf[ni] = *(const short8*)&Bs2[buf][n * 64 + (((ks * 4 + l4) ^ (n & 7)) << 3)];
            }
#pragma unroll
            for (int mi = 0; mi < 4; ++mi)
#pragma unroll
                for (int ni = 0; ni < 4; ++ni)
                    acc[mi][ni] = __builtin_amdgcn_mfma_f32_16x16x32_bf16(
                        af[mi], bf[ni], acc[mi][ni], 0, 0, 0);
        }
    };
    load_a(0); load_b(0); write_a(0); write_b(0);
    __syncthreads();
    int buf = 0;
    for (int kt = 0; kt < NKT; ++kt) {
        const bool more = (kt + 1 < NKT);
        if (more) { load_a(kt + 1); load_b(kt + 1); }
        compute(buf);
        if (more) { write_a(buf ^ 1); write_b(buf ^ 1); }
        __syncthreads();
        buf ^= 1;
    }
#pragma unroll
    for (int mi = 0; mi < 4; ++mi) {
        const int rbase = row0 + wm * 64 + mi * 16 + l4 * 4;
#pragma unroll
        for (int ni = 0; ni < 4; ++ni) {
            const int c = col0 + wn * 64 + ni * 16 + l15;
#pragma unroll
            for (int r = 0; r < 4; ++r)
                out[(size_t)(rbase + r) * Nd + c] = acc[mi][ni][r];
        }
    }
}

extern "C" void kernel_launch(void* const* d_in, const int* in_sizes, int n_in,
                              void* d_out, int out_size, void* d_ws, size_t ws_size,
                              hipStream_t stream) {
    const float* H = (const float*)d_in[0];
    const float* W = (const float*)d_in[1];
    const int* counts = (const int*)d_in[2];
    float* out = (float*)d_out;
    const size_t need = (size_t)(Tt * Kd + Gn * Kd * Nd) * sizeof(short); // 32 MB
    if (ws_size >= need) {
        short* Hb = (short*)d_ws;
        short* Wt = Hb + (size_t)Tt * Kd;
        prep_kernel<<<3072, 256, 0, stream>>>(H, W, Hb, Wt);
        gemm_kernel<<<512, 256, 0, stream>>>(Hb, Wt, counts, out);
    } else {
        gemm_f32_fallback<<<256, 512, 0, stream>>>(H, W, counts, out);
    }
}